// Round 1
// 552.250 us; speedup vs baseline: 1.4356x; 1.4356x over previous
//
#include <hip/hip_runtime.h>
#include <math.h>

#define NB   4096
#define LL   50
#define FF   128
#define HH   8
#define DVn  16

typedef __attribute__((ext_vector_type(8))) short bf16x8;
typedef __attribute__((ext_vector_type(4))) float f32x4;

__device__ __forceinline__ ushort bf_hi(float x) {
    uint u = __float_as_uint(x);
    uint r = u + 0x7FFFu + ((u >> 16) & 1u);   // RTNE to bf16
    return (ushort)(r >> 16);
}
__device__ __forceinline__ float bf_f(ushort b) { return __uint_as_float(((uint)b) << 16); }

// ---------------- pack: M = Wq Wk^T, u = Wq bk, v = Wk bq, c = bq.bk, Wv ----
// wp frag layout per head: tiles 0..7 = M n-cols, 8 = [u|v|0..], 9 = Wv.
//   tile stride 4096 u, ks stride 1024, part(hi/lo) stride 512, lane*8.
// c[] floats at ushort offset 327680.
// v2: Wq/Wk staged in LDS (pad 129 -> conflict-free reads; identical e order so
//     M is bit-identical); tile==8 u/v parallelized over e + butterfly reduce;
//     cc computed wave-parallel. Was ~100us (unhidden global-load latency),
//     target ~10us.
__global__ __launch_bounds__(256)
void pack_w(const float* __restrict__ Wq, const float* __restrict__ bq,
            const float* __restrict__ Wk, const float* __restrict__ bk,
            const float* __restrict__ Wv, ushort* __restrict__ wp)
{
    __shared__ float sw[128*129 + 16*129];     // 74304 B
    const int t    = threadIdx.x;
    const int lane = t & 63;
    const int ks   = t >> 6;
    const int h    = blockIdx.x / 10;
    const int tile = blockIdx.x % 10;
    const int c    = lane & 15;
    const int f0   = ks*32 + (lane >> 4)*8;

    float val[8];
    #pragma unroll
    for (int j = 0; j < 8; ++j) val[j] = 0.f;

    if (tile < 8) {                                 // M[f][g] = sum_e Wq[f][e] Wk[g][e]
        const float* wq = Wq + (size_t)h*FF*FF;
        const float* wk = Wk + (size_t)h*FF*FF;
        float* wqs = sw;
        float* wks = sw + 128*129;
        for (int i = t; i < 128*128; i += 256)
            wqs[(i>>7)*129 + (i&127)] = wq[i];
        for (int i = t; i < 16*128;  i += 256)
            wks[(i>>7)*129 + (i&127)] = wk[(size_t)(tile*16 + (i>>7))*FF + (i&127)];
        __syncthreads();
        for (int e = 0; e < FF; ++e) {              // identical order -> bit-identical M
            float kv = wks[c*129 + e];
            #pragma unroll
            for (int j = 0; j < 8; ++j) val[j] += wqs[(f0+j)*129 + e] * kv;
        }
    } else if (tile == 8) {                         // col0 = u = Wq bk, col1 = v = Wk bq
        const float* wq = Wq + (size_t)h*FF*FF;
        const float* wk = Wk + (size_t)h*FF*FF;
        float pu[8], pv[8];
        #pragma unroll
        for (int j = 0; j < 8; ++j) { pu[j] = 0.f; pv[j] = 0.f; }
        for (int ee = 0; ee < 8; ++ee) {            // lane c handles e in [8c, 8c+8)
            int e = c*8 + ee;
            float bkk = bk[h*FF + e], bqq = bq[h*FF + e];
            #pragma unroll
            for (int j = 0; j < 8; ++j) {
                pu[j] += wq[(size_t)(f0+j)*FF + e] * bkk;
                pv[j] += wk[(size_t)(f0+j)*FF + e] * bqq;
            }
        }
        #pragma unroll
        for (int m = 1; m < 16; m <<= 1) {          // reduce over c (quad preserved)
            #pragma unroll
            for (int j = 0; j < 8; ++j) {
                pu[j] += __shfl_xor(pu[j], m);
                pv[j] += __shfl_xor(pv[j], m);
            }
        }
        if (c == 0) {
            #pragma unroll
            for (int j = 0; j < 8; ++j) val[j] = pu[j];
        } else if (c == 1) {
            #pragma unroll
            for (int j = 0; j < 8; ++j) val[j] = pv[j];
        }
        if (ks == 0) {                              // c = bq.bk, wave-parallel
            float s = bq[h*FF + lane*2]*bk[h*FF + lane*2]
                    + bq[h*FF + lane*2 + 1]*bk[h*FF + lane*2 + 1];
            #pragma unroll
            for (int m = 1; m < 64; m <<= 1) s += __shfl_xor(s, m);
            if (lane == 0) ((float*)(wp + 327680))[h] = s;
        }
    } else {                                        // Wv B-frag
        const float* wv = Wv + (size_t)h*FF*DVn;
        #pragma unroll
        for (int j = 0; j < 8; ++j) val[j] = wv[(size_t)(f0+j)*DVn + c];
    }

    ushort hi[8], lo[8];
    #pragma unroll
    for (int j = 0; j < 8; ++j) {
        ushort hb = bf_hi(val[j]);
        hi[j] = hb;
        lo[j] = bf_hi(val[j] - bf_f(hb));
    }
    size_t base = (size_t)h*40960 + (size_t)tile*4096 + ks*1024 + lane*8;
    *(ushort4*)(wp + base)       = make_ushort4(hi[0],hi[1],hi[2],hi[3]);
    *(ushort4*)(wp + base + 4)   = make_ushort4(hi[4],hi[5],hi[6],hi[7]);
    *(ushort4*)(wp + base + 512) = make_ushort4(lo[0],lo[1],lo[2],lo[3]);
    *(ushort4*)(wp + base + 516) = make_ushort4(lo[4],lo[5],lo[6],lo[7]);
}

// ---------------- fused attention ----------------
// v2: one block per b, h-loop inside (x staged+converted ONCE, was 8x);
//     T-frag panels group-XOR-swizzled (g^=((g>>4)&1)<<1) to kill 4-way epilogue
//     write conflicts; satt stride 80->88 us (quad term 16 mod 32, <=2-way).
// LDS (ushorts; 81408 B total -> 2 blocks/CU, 162816 <= 163840):
//   xh panels [mt4][ks4] @0, xl @8448    (panel stride 528)
//   th @16896, tl @25344  (T hi/lo frag panels, swizzled groups)
//   vf @33792 (2 ks panels x 512, V B-frag bf16, hi only)
//   satt bf16 [64][88] @34816
//   tu[64],tv[64] fp32 @float 20224/20288
#define PX    528
#define XH0   0
#define XL0   8448
#define TH0   16896
#define TL0   25344
#define VF0   33792
#define SATT0 34816
#define SATTP 88
#define TU0   20224
#define TV0   20288
#define LDS_FLOATS 20352

__global__ __launch_bounds__(256, 2)
void attn_fused(const float* __restrict__ hid, const ushort* __restrict__ wp,
                const float* __restrict__ ccp, const float* __restrict__ bv,
                float* __restrict__ out)
{
    __shared__ __align__(16) float lds[LDS_FLOATS];
    ushort* us = (ushort*)lds;
    float*  tu = lds + TU0;
    float*  tv = lds + TV0;

    const int t    = threadIdx.x;
    const int b    = blockIdx.x;
    const int lane = t & 63;
    const int w    = t >> 6;
    const int c16  = lane & 15;
    const int quad = lane >> 4;
    // swizzled T-frag group offset for reads (matches epilogue write swizzle)
    const int lsw8 = (lane ^ (((lane >> 4) & 1) << 1)) * 8;

    // ---- stage x -> bf16 hi/lo A-frag panels, ONCE per b (rows>=50 garbage; masked) ----
    {
        const float4* src = (const float4*)(hid + (size_t)b * (LL*FF));
        for (int i = t; i < 1600; i += 256) {
            float4 v = src[i];
            int l = i >> 5, f0 = (i & 31) * 4;
            int slot = ((l>>4)*4 + (f0>>5))*PX + ((l&15) + 16*((f0&31)>>3))*8 + (f0&7);
            ushort4 hv, lv;
            hv.x = bf_hi(v.x); lv.x = bf_hi(v.x - bf_f(hv.x));
            hv.y = bf_hi(v.y); lv.y = bf_hi(v.y - bf_f(hv.y));
            hv.z = bf_hi(v.z); lv.z = bf_hi(v.z - bf_f(hv.z));
            hv.w = bf_hi(v.w); lv.w = bf_hi(v.w - bf_f(hv.w));
            *(ushort4*)(us + XH0 + slot) = hv;
            *(ushort4*)(us + XL0 + slot) = lv;
        }
    }
    __syncthreads();

    #pragma unroll 1
    for (int h = 0; h < HH; ++h) {
        // ---- T = x.[M|u|v], V = x.Wv  (bf16x3 / x1 / x2). Wave w: n-tiles {2w,2w+1} ----
        f32x4 aT[4][2], aU, aV;
        #pragma unroll
        for (int m = 0; m < 4; ++m) {
            aT[m][0] = (f32x4){0.f,0.f,0.f,0.f};
            aT[m][1] = (f32x4){0.f,0.f,0.f,0.f};
        }
        aU = (f32x4){0.f,0.f,0.f,0.f};
        aV = (f32x4){0.f,0.f,0.f,0.f};

        const ushort* wb = wp + (size_t)h*40960 + lane*8;
        #define WFRG(tt,kk,pp) (*(const bf16x8*)(wb + (size_t)(tt)*4096 + (kk)*1024 + (pp)*512))

        for (int ks = 0; ks < 4; ++ks) {
            bf16x8 m0h = WFRG(2*w,   ks, 0), m0l = WFRG(2*w,   ks, 1);
            bf16x8 m1h = WFRG(2*w+1, ks, 0), m1l = WFRG(2*w+1, ks, 1);
            bf16x8 uvh = WFRG(8, ks, 0);
            bf16x8 vvh = WFRG(9, ks, 0);
            #pragma unroll
            for (int mt = 0; mt < 4; ++mt) {
                const ushort* xp = us + XH0 + (mt*4 + ks)*PX + lane*8;
                bf16x8 ah = *(const bf16x8*)xp;
                bf16x8 al = *(const bf16x8*)(xp + XL0);
                aT[mt][0] = __builtin_amdgcn_mfma_f32_16x16x32_bf16(ah, m0h, aT[mt][0], 0,0,0);
                aT[mt][0] = __builtin_amdgcn_mfma_f32_16x16x32_bf16(ah, m0l, aT[mt][0], 0,0,0);
                aT[mt][0] = __builtin_amdgcn_mfma_f32_16x16x32_bf16(al, m0h, aT[mt][0], 0,0,0);
                aT[mt][1] = __builtin_amdgcn_mfma_f32_16x16x32_bf16(ah, m1h, aT[mt][1], 0,0,0);
                aT[mt][1] = __builtin_amdgcn_mfma_f32_16x16x32_bf16(ah, m1l, aT[mt][1], 0,0,0);
                aT[mt][1] = __builtin_amdgcn_mfma_f32_16x16x32_bf16(al, m1h, aT[mt][1], 0,0,0);
                if (mt == w) {
                    aU = __builtin_amdgcn_mfma_f32_16x16x32_bf16(ah, uvh, aU, 0,0,0);
                    aV = __builtin_amdgcn_mfma_f32_16x16x32_bf16(ah, vvh, aV, 0,0,0);
                    aV = __builtin_amdgcn_mfma_f32_16x16x32_bf16(al, vvh, aV, 0,0,0);
                }
            }
        }

        // ---- epilogue: T -> hi/lo frag panels (ks = w, XOR-swizzled); tu/tv; V B-frag ----
        {
            const int jj   = c16 & 7;
            const int hi16 = c16 >> 3;
            const int sw2  = hi16 << 1;            // XOR into bit1 of row-in-16
            #pragma unroll
            for (int nt = 0; nt < 2; ++nt) {
                #pragma unroll
                for (int mt = 0; mt < 4; ++mt) {
                    int pb = (mt*4 + w)*PX + jj;
                    #pragma unroll
                    for (int r = 0; r < 4; ++r) {
                        int grp = ((quad*4 + r) ^ sw2) + 16*(nt*2 + hi16);
                        int idx = pb + grp*8;
                        float tval = aT[mt][nt][r];
                        ushort th_ = bf_hi(tval);
                        us[TH0 + idx] = th_;
                        us[TL0 + idx] = bf_hi(tval - bf_f(th_));
                    }
                }
            }
            if (c16 < 2) {
                float* dst = (c16 == 0) ? tu : tv;
                #pragma unroll
                for (int r = 0; r < 4; ++r) dst[w*16 + quad*4 + r] = aU[r];
            }
            float bvv = bv[h*DVn + c16];
            int ksp = w >> 1;
            #pragma unroll
            for (int r = 0; r < 4; ++r) {
                int m  = w*16 + quad*4 + r;
                int mm = (w&1)*16 + quad*4 + r;
                int Lp = c16 + 16*(mm >> 3);
                us[VF0 + ksp*512 + Lp*8 + (mm & 7)] = (m < LL) ? bf_hi(aV[r] + bvv) : (ushort)0;
            }
        }
        __syncthreads();

        // ---- scores: S = T x^T (bf16x3). Wave w: col tile w ----
        f32x4 sc[4];
        #pragma unroll
        for (int m = 0; m < 4; ++m) sc[m] = (f32x4){0.f,0.f,0.f,0.f};

        for (int ks = 0; ks < 4; ++ks) {
            const ushort* xb = us + XH0 + (w*4 + ks)*PX + lane*8;
            bf16x8 bh = *(const bf16x8*)xb;
            bf16x8 bl = *(const bf16x8*)(xb + XL0);
            #pragma unroll
            for (int mt = 0; mt < 4; ++mt) {
                const ushort* tb = us + TH0 + (mt*4 + ks)*PX + lsw8;
                bf16x8 th = *(const bf16x8*)tb;
                bf16x8 tl = *(const bf16x8*)(tb + XL0);   // TL0-TH0 == XL0
                sc[mt] = __builtin_amdgcn_mfma_f32_16x16x32_bf16(th, bh, sc[mt], 0,0,0);
                sc[mt] = __builtin_amdgcn_mfma_f32_16x16x32_bf16(tl, bh, sc[mt], 0,0,0);
                sc[mt] = __builtin_amdgcn_mfma_f32_16x16x32_bf16(th, bl, sc[mt], 0,0,0);
            }
        }

        // ---- add rank-1/const terms, leaky, column softmax (over l) ----
        const float cc  = ccp[h];
        const int mcol  = w*16 + c16;
        const float tvv = tv[mcol] + cc;
        float mx = -INFINITY;
        #pragma unroll
        for (int mt = 0; mt < 4; ++mt)
            #pragma unroll
            for (int r = 0; r < 4; ++r) {
                int l = mt*16 + quad*4 + r;
                float s = sc[mt][r] + tu[l] + tvv;
                s = (s > 0.f) ? s : 0.1f*s;
                sc[mt][r] = s;
                if (l < LL) mx = fmaxf(mx, s);
            }
        mx = fmaxf(mx, __shfl_xor(mx, 16));
        mx = fmaxf(mx, __shfl_xor(mx, 32));
        float sum = 0.f;
        #pragma unroll
        for (int mt = 0; mt < 4; ++mt)
            #pragma unroll
            for (int r = 0; r < 4; ++r) {
                int l = mt*16 + quad*4 + r;
                float p = (l < LL) ? __expf(sc[mt][r] - mx) : 0.f;
                sc[mt][r] = p;
                sum += p;
            }
        sum += __shfl_xor(sum, 16);
        sum += __shfl_xor(sum, 32);
        float inv = 1.0f / sum;

        // satt bf16 [64][88]; cols >=50 zeroed (keeps NaN out of PV)
        #pragma unroll
        for (int mt = 0; mt < 4; ++mt)
            #pragma unroll
            for (int r = 0; r < 4; ++r) {
                int l = mt*16 + quad*4 + r;
                us[SATT0 + l*SATTP + mcol] = (mcol < LL) ? bf_hi(sc[mt][r] * inv) : (ushort)0;
            }
        __syncthreads();

        // ---- out = relu(att.V) via MFMA; wave w owns l-tile w ----
        f32x4 ao = (f32x4){0.f,0.f,0.f,0.f};
        #pragma unroll
        for (int ksp = 0; ksp < 2; ++ksp) {
            bf16x8 af = *(const bf16x8*)(us + SATT0 + (w*16 + c16)*SATTP + ksp*32 + quad*8);
            bf16x8 bf = *(const bf16x8*)(us + VF0 + ksp*512 + lane*8);
            ao = __builtin_amdgcn_mfma_f32_16x16x32_bf16(af, bf, ao, 0,0,0);
        }
        #pragma unroll
        for (int r = 0; r < 4; ++r) {
            int l = w*16 + quad*4 + r;
            if (l < LL)
                out[(size_t)b*(LL*FF) + l*FF + h*DVn + c16] = fmaxf(ao[r], 0.f);
        }
        __syncthreads();   // protect satt/vf/tu/tv before next h's epilogue writes
    }
}

extern "C" void kernel_launch(void* const* d_in, const int* in_sizes, int n_in,
                              void* d_out, int out_size, void* d_ws, size_t ws_size,
                              hipStream_t stream)
{
    const float* hid = (const float*)d_in[0];
    const float* Wq  = (const float*)d_in[1];
    const float* bq  = (const float*)d_in[2];
    const float* Wk  = (const float*)d_in[3];
    const float* bk  = (const float*)d_in[4];
    const float* Wv  = (const float*)d_in[5];
    const float* bv  = (const float*)d_in[6];
    float* o    = (float*)d_out;
    ushort* wp  = (ushort*)d_ws;                       // 655392 B used
    const float* ccp = (const float*)(wp + 327680);

    pack_w<<<dim3(80), dim3(256), 0, stream>>>(Wq, bq, Wk, bk, Wv, wp);
    attn_fused<<<dim3(NB), dim3(256), 0, stream>>>(hid, wp, ccp, bv, o);
}

// Round 2
// 505.396 us; speedup vs baseline: 1.5687x; 1.0927x over previous
//
#include <hip/hip_runtime.h>
#include <math.h>

#define NB   4096
#define LL   50
#define FF   128
#define HH   8
#define DVn  16

typedef __attribute__((ext_vector_type(8))) short bf16x8;
typedef __attribute__((ext_vector_type(4))) float f32x4;

__device__ __forceinline__ ushort bf_hi(float x) {
    uint u = __float_as_uint(x);
    uint r = u + 0x7FFFu + ((u >> 16) & 1u);   // RTNE to bf16
    return (ushort)(r >> 16);
}
__device__ __forceinline__ float bf_f(ushort b) { return __uint_as_float(((uint)b) << 16); }

// ---------------- pack: M = Wq Wk^T, u = Wq bk, v = Wk bq, c = bq.bk, Wv ----
// (unchanged from v2 — Wq/Wk staged in LDS, bit-identical M)
__global__ __launch_bounds__(256)
void pack_w(const float* __restrict__ Wq, const float* __restrict__ bq,
            const float* __restrict__ Wk, const float* __restrict__ bk,
            const float* __restrict__ Wv, ushort* __restrict__ wp)
{
    __shared__ float sw[128*129 + 16*129];     // 74304 B
    const int t    = threadIdx.x;
    const int lane = t & 63;
    const int ks   = t >> 6;
    const int h    = blockIdx.x / 10;
    const int tile = blockIdx.x % 10;
    const int c    = lane & 15;
    const int f0   = ks*32 + (lane >> 4)*8;

    float val[8];
    #pragma unroll
    for (int j = 0; j < 8; ++j) val[j] = 0.f;

    if (tile < 8) {                                 // M[f][g] = sum_e Wq[f][e] Wk[g][e]
        const float* wq = Wq + (size_t)h*FF*FF;
        const float* wk = Wk + (size_t)h*FF*FF;
        float* wqs = sw;
        float* wks = sw + 128*129;
        for (int i = t; i < 128*128; i += 256)
            wqs[(i>>7)*129 + (i&127)] = wq[i];
        for (int i = t; i < 16*128;  i += 256)
            wks[(i>>7)*129 + (i&127)] = wk[(size_t)(tile*16 + (i>>7))*FF + (i&127)];
        __syncthreads();
        for (int e = 0; e < FF; ++e) {              // identical order -> bit-identical M
            float kv = wks[c*129 + e];
            #pragma unroll
            for (int j = 0; j < 8; ++j) val[j] += wqs[(f0+j)*129 + e] * kv;
        }
    } else if (tile == 8) {                         // col0 = u = Wq bk, col1 = v = Wk bq
        const float* wq = Wq + (size_t)h*FF*FF;
        const float* wk = Wk + (size_t)h*FF*FF;
        float pu[8], pv[8];
        #pragma unroll
        for (int j = 0; j < 8; ++j) { pu[j] = 0.f; pv[j] = 0.f; }
        for (int ee = 0; ee < 8; ++ee) {            // lane c handles e in [8c, 8c+8)
            int e = c*8 + ee;
            float bkk = bk[h*FF + e], bqq = bq[h*FF + e];
            #pragma unroll
            for (int j = 0; j < 8; ++j) {
                pu[j] += wq[(size_t)(f0+j)*FF + e] * bkk;
                pv[j] += wk[(size_t)(f0+j)*FF + e] * bqq;
            }
        }
        #pragma unroll
        for (int m = 1; m < 16; m <<= 1) {          // reduce over c (quad preserved)
            #pragma unroll
            for (int j = 0; j < 8; ++j) {
                pu[j] += __shfl_xor(pu[j], m);
                pv[j] += __shfl_xor(pv[j], m);
            }
        }
        if (c == 0) {
            #pragma unroll
            for (int j = 0; j < 8; ++j) val[j] = pu[j];
        } else if (c == 1) {
            #pragma unroll
            for (int j = 0; j < 8; ++j) val[j] = pv[j];
        }
        if (ks == 0) {                              // c = bq.bk, wave-parallel
            float s = bq[h*FF + lane*2]*bk[h*FF + lane*2]
                    + bq[h*FF + lane*2 + 1]*bk[h*FF + lane*2 + 1];
            #pragma unroll
            for (int m = 1; m < 64; m <<= 1) s += __shfl_xor(s, m);
            if (lane == 0) ((float*)(wp + 327680))[h] = s;
        }
    } else {                                        // Wv B-frag
        const float* wv = Wv + (size_t)h*FF*DVn;
        #pragma unroll
        for (int j = 0; j < 8; ++j) val[j] = wv[(size_t)(f0+j)*DVn + c];
    }

    ushort hi[8], lo[8];
    #pragma unroll
    for (int j = 0; j < 8; ++j) {
        ushort hb = bf_hi(val[j]);
        hi[j] = hb;
        lo[j] = bf_hi(val[j] - bf_f(hb));
    }
    size_t base = (size_t)h*40960 + (size_t)tile*4096 + ks*1024 + lane*8;
    *(ushort4*)(wp + base)       = make_ushort4(hi[0],hi[1],hi[2],hi[3]);
    *(ushort4*)(wp + base + 4)   = make_ushort4(hi[4],hi[5],hi[6],hi[7]);
    *(ushort4*)(wp + base + 512) = make_ushort4(lo[0],lo[1],lo[2],lo[3]);
    *(ushort4*)(wp + base + 516) = make_ushort4(lo[4],lo[5],lo[6],lo[7]);
}

// ---------------- fused attention ----------------
// v3: x-hi A-frags held in REGISTERS (preloaded once; 64 VGPR) -> kills 20 of 76
//     ds_read_b128 per wave per h; xh staging region overlaid by th/tl, satt
//     overlaid on th (extra barrier) -> LDS 81408 -> 53248 B -> 3 blocks/CU.
// LDS (ushorts; 53248 B):
//   xl panels [mt4][ks4] @0 (persist, stride 528)
//   xh staging @8448 (dead after reg preload) == th @8448, tl @16896
//   satt bf16 [64][88] @8448 (overlay th; barrier-separated)
//   vf @25344 (2 ks panels x 512, V B-frag bf16)
//   tu[64],tv[64] fp32 @float 13184/13248
#define PX    528
#define XL0   0
#define XH0   8448
#define TH0   8448
#define TDEL  8448
#define SATT0 8448
#define VF0   25344
#define SATTP 88
#define TU0   13184
#define TV0   13248
#define LDS_FLOATS 13312

__global__ __launch_bounds__(256, 3)
void attn_fused(const float* __restrict__ hid, const ushort* __restrict__ wp,
                const float* __restrict__ ccp, const float* __restrict__ bv,
                float* __restrict__ out)
{
    __shared__ __align__(16) float lds[LDS_FLOATS];
    ushort* us = (ushort*)lds;
    float*  tu = lds + TU0;
    float*  tv = lds + TV0;

    const int t    = threadIdx.x;
    const int b    = blockIdx.x;
    const int lane = t & 63;
    const int w    = t >> 6;
    const int c16  = lane & 15;
    const int quad = lane >> 4;
    const int lsw8 = (lane ^ (((lane >> 4) & 1) << 1)) * 8;   // swizzled T-read offset

    // ---- stage x -> bf16 hi/lo A-frag panels, ONCE per b ----
    {
        const float4* src = (const float4*)(hid + (size_t)b * (LL*FF));
        for (int i = t; i < 1600; i += 256) {
            float4 v = src[i];
            int l = i >> 5, f0 = (i & 31) * 4;
            int slot = ((l>>4)*4 + (f0>>5))*PX + ((l&15) + 16*((f0&31)>>3))*8 + (f0&7);
            ushort4 hv, lv;
            hv.x = bf_hi(v.x); lv.x = bf_hi(v.x - bf_f(hv.x));
            hv.y = bf_hi(v.y); lv.y = bf_hi(v.y - bf_f(hv.y));
            hv.z = bf_hi(v.z); lv.z = bf_hi(v.z - bf_f(hv.z));
            hv.w = bf_hi(v.w); lv.w = bf_hi(v.w - bf_f(hv.w));
            *(ushort4*)(us + XH0 + slot) = hv;
            *(ushort4*)(us + XL0 + slot) = lv;
        }
    }
    __syncthreads();

    // ---- preload ALL 16 x-hi A-frags into registers (xh region dies after this) ----
    bf16x8 xh[16];
    #pragma unroll
    for (int i = 0; i < 16; ++i)
        xh[i] = *(const bf16x8*)(us + XH0 + i*PX + lane*8);
    __syncthreads();

    #pragma unroll 1
    for (int h = 0; h < HH; ++h) {
        // ---- T = x.[M|u|v], V = x.Wv. Wave w: n-tiles {2w,2w+1} ----
        f32x4 aT[4][2], aU, aV;
        #pragma unroll
        for (int m = 0; m < 4; ++m) {
            aT[m][0] = (f32x4){0.f,0.f,0.f,0.f};
            aT[m][1] = (f32x4){0.f,0.f,0.f,0.f};
        }
        aU = (f32x4){0.f,0.f,0.f,0.f};
        aV = (f32x4){0.f,0.f,0.f,0.f};

        const ushort* wb = wp + (size_t)h*40960 + lane*8;
        #define WFRG(tt,kk,pp) (*(const bf16x8*)(wb + (size_t)(tt)*4096 + (kk)*1024 + (pp)*512))

        #pragma unroll
        for (int ks = 0; ks < 4; ++ks) {
            bf16x8 m0h = WFRG(2*w,   ks, 0), m0l = WFRG(2*w,   ks, 1);
            bf16x8 m1h = WFRG(2*w+1, ks, 0), m1l = WFRG(2*w+1, ks, 1);
            bf16x8 uvh = WFRG(8, ks, 0);
            bf16x8 vvh = WFRG(9, ks, 0);
            #pragma unroll
            for (int mt = 0; mt < 4; ++mt) {
                bf16x8 ah = xh[mt*4 + ks];                       // static index
                bf16x8 al = *(const bf16x8*)(us + XL0 + (mt*4 + ks)*PX + lane*8);
                aT[mt][0] = __builtin_amdgcn_mfma_f32_16x16x32_bf16(ah, m0h, aT[mt][0], 0,0,0);
                aT[mt][0] = __builtin_amdgcn_mfma_f32_16x16x32_bf16(ah, m0l, aT[mt][0], 0,0,0);
                aT[mt][0] = __builtin_amdgcn_mfma_f32_16x16x32_bf16(al, m0h, aT[mt][0], 0,0,0);
                aT[mt][1] = __builtin_amdgcn_mfma_f32_16x16x32_bf16(ah, m1h, aT[mt][1], 0,0,0);
                aT[mt][1] = __builtin_amdgcn_mfma_f32_16x16x32_bf16(ah, m1l, aT[mt][1], 0,0,0);
                aT[mt][1] = __builtin_amdgcn_mfma_f32_16x16x32_bf16(al, m1h, aT[mt][1], 0,0,0);
                if (mt == w) {
                    aU = __builtin_amdgcn_mfma_f32_16x16x32_bf16(ah, uvh, aU, 0,0,0);
                    aV = __builtin_amdgcn_mfma_f32_16x16x32_bf16(ah, vvh, aV, 0,0,0);
                    aV = __builtin_amdgcn_mfma_f32_16x16x32_bf16(al, vvh, aV, 0,0,0);
                }
            }
        }

        // ---- epilogue: T -> hi/lo frag panels (ks = w, XOR-swizzled); tu/tv; V B-frag ----
        {
            const int jj   = c16 & 7;
            const int hi16 = c16 >> 3;
            const int sw2  = hi16 << 1;
            #pragma unroll
            for (int nt = 0; nt < 2; ++nt) {
                #pragma unroll
                for (int mt = 0; mt < 4; ++mt) {
                    int pb = (mt*4 + w)*PX + jj;
                    #pragma unroll
                    for (int r = 0; r < 4; ++r) {
                        int grp = ((quad*4 + r) ^ sw2) + 16*(nt*2 + hi16);
                        int idx = pb + grp*8;
                        float tval = aT[mt][nt][r];
                        ushort th_ = bf_hi(tval);
                        us[TH0 + idx]        = th_;
                        us[TH0 + TDEL + idx] = bf_hi(tval - bf_f(th_));
                    }
                }
            }
            if (c16 < 2) {
                float* dst = (c16 == 0) ? tu : tv;
                #pragma unroll
                for (int r = 0; r < 4; ++r) dst[w*16 + quad*4 + r] = aU[r];
            }
            float bvv = bv[h*DVn + c16];
            int ksp = w >> 1;
            #pragma unroll
            for (int r = 0; r < 4; ++r) {
                int m  = w*16 + quad*4 + r;
                int mm = (w&1)*16 + quad*4 + r;
                int Lp = c16 + 16*(mm >> 3);
                us[VF0 + ksp*512 + Lp*8 + (mm & 7)] = (m < LL) ? bf_hi(aV[r] + bvv) : (ushort)0;
            }
        }
        __syncthreads();                            // (c) th/tl/vf/tu/tv visible

        // ---- scores: S = T x^T. Wave w: col tile w; bh from regs (static via branch) ----
        f32x4 sc[4];
        #pragma unroll
        for (int m = 0; m < 4; ++m) sc[m] = (f32x4){0.f,0.f,0.f,0.f};

        #pragma unroll
        for (int cw = 0; cw < 4; ++cw) if (w == cw) {
            #pragma unroll
            for (int ks = 0; ks < 4; ++ks) {
                bf16x8 bh = xh[cw*4 + ks];                       // static index
                bf16x8 bl = *(const bf16x8*)(us + XL0 + (cw*4 + ks)*PX + lane*8);
                #pragma unroll
                for (int mt = 0; mt < 4; ++mt) {
                    const ushort* tb = us + TH0 + (mt*4 + ks)*PX + lsw8;
                    bf16x8 th = *(const bf16x8*)tb;
                    bf16x8 tl = *(const bf16x8*)(tb + TDEL);
                    sc[mt] = __builtin_amdgcn_mfma_f32_16x16x32_bf16(th, bh, sc[mt], 0,0,0);
                    sc[mt] = __builtin_amdgcn_mfma_f32_16x16x32_bf16(tl, bh, sc[mt], 0,0,0);
                    sc[mt] = __builtin_amdgcn_mfma_f32_16x16x32_bf16(th, bl, sc[mt], 0,0,0);
                }
            }
        }

        // ---- rank-1/const terms, leaky, column softmax (registers only) ----
        const float cc  = ccp[h];
        const int mcol  = w*16 + c16;
        const float tvv = tv[mcol] + cc;
        float mx = -INFINITY;
        #pragma unroll
        for (int mt = 0; mt < 4; ++mt)
            #pragma unroll
            for (int r = 0; r < 4; ++r) {
                int l = mt*16 + quad*4 + r;
                float s = sc[mt][r] + tu[l] + tvv;
                s = (s > 0.f) ? s : 0.1f*s;
                sc[mt][r] = s;
                if (l < LL) mx = fmaxf(mx, s);
            }
        mx = fmaxf(mx, __shfl_xor(mx, 16));
        mx = fmaxf(mx, __shfl_xor(mx, 32));
        float sum = 0.f;
        #pragma unroll
        for (int mt = 0; mt < 4; ++mt)
            #pragma unroll
            for (int r = 0; r < 4; ++r) {
                int l = mt*16 + quad*4 + r;
                float p = (l < LL) ? __expf(sc[mt][r] - mx) : 0.f;
                sc[mt][r] = p;
                sum += p;
            }
        sum += __shfl_xor(sum, 16);
        sum += __shfl_xor(sum, 32);
        float inv = 1.0f / sum;

        __syncthreads();                            // (e) all T reads done before satt overlay

        // satt bf16 [64][88] overlaid on th; cols >=50 zeroed
        #pragma unroll
        for (int mt = 0; mt < 4; ++mt)
            #pragma unroll
            for (int r = 0; r < 4; ++r) {
                int l = mt*16 + quad*4 + r;
                us[SATT0 + l*SATTP + mcol] = (mcol < LL) ? bf_hi(sc[mt][r] * inv) : (ushort)0;
            }
        __syncthreads();                            // (g) satt visible

        // ---- out = relu(att.V) via MFMA; wave w owns l-tile w ----
        f32x4 ao = (f32x4){0.f,0.f,0.f,0.f};
        #pragma unroll
        for (int ksp = 0; ksp < 2; ++ksp) {
            bf16x8 af = *(const bf16x8*)(us + SATT0 + (w*16 + c16)*SATTP + ksp*32 + quad*8);
            bf16x8 bf = *(const bf16x8*)(us + VF0 + ksp*512 + lane*8);
            ao = __builtin_amdgcn_mfma_f32_16x16x32_bf16(af, bf, ao, 0,0,0);
        }
        #pragma unroll
        for (int r = 0; r < 4; ++r) {
            int l = w*16 + quad*4 + r;
            if (l < LL)
                out[(size_t)b*(LL*FF) + l*FF + h*DVn + c16] = fmaxf(ao[r], 0.f);
        }
        __syncthreads();                            // (i) protect satt/vf/tu/tv for next h
    }
}

extern "C" void kernel_launch(void* const* d_in, const int* in_sizes, int n_in,
                              void* d_out, int out_size, void* d_ws, size_t ws_size,
                              hipStream_t stream)
{
    const float* hid = (const float*)d_in[0];
    const float* Wq  = (const float*)d_in[1];
    const float* bq  = (const float*)d_in[2];
    const float* Wk  = (const float*)d_in[3];
    const float* bk  = (const float*)d_in[4];
    const float* Wv  = (const float*)d_in[5];
    const float* bv  = (const float*)d_in[6];
    float* o    = (float*)d_out;
    ushort* wp  = (ushort*)d_ws;                       // 655392 B used
    const float* ccp = (const float*)(wp + 327680);

    pack_w<<<dim3(80), dim3(256), 0, stream>>>(Wq, bq, Wk, bk, Wv, wp);
    attn_fused<<<dim3(NB), dim3(256), 0, stream>>>(hid, wp, ccp, bv, o);
}

// Round 3
// 478.730 us; speedup vs baseline: 1.6561x; 1.0557x over previous
//
#include <hip/hip_runtime.h>
#include <math.h>

#define NB   4096
#define LL   50
#define FF   128
#define HH   8
#define DVn  16

typedef __attribute__((ext_vector_type(8))) short bf16x8;
typedef __attribute__((ext_vector_type(4))) float f32x4;

__device__ __forceinline__ ushort bf_hi(float x) {
    uint u = __float_as_uint(x);
    uint r = u + 0x7FFFu + ((u >> 16) & 1u);   // RTNE to bf16
    return (ushort)(r >> 16);
}
__device__ __forceinline__ float bf_f(ushort b) { return __uint_as_float(((uint)b) << 16); }

// ---------------- pack: M = Wq Wk^T (A-frag!), u = Wq bk, v = Wk bq, c = bq.bk, Wv ----
// v4: M stored as A-FRAGS for G = M.x^T: val[j] = M[16*tile + (lane&15)][32*ks + quad*8 + j].
//     Grid 320 = 8h x 10tile x 4ks, 64 threads; per-slice LDS staging (24768 B).
//     Tiles 8 (u|v) and 9 (Wv) remain B-frags, unchanged semantics.
// wp frag addressing unchanged: h*40960 + tile*4096 + ks*1024 + part*512 + lane*8.
// c[] floats at ushort offset 327680.
__global__ __launch_bounds__(64)
void pack_w(const float* __restrict__ Wq, const float* __restrict__ bq,
            const float* __restrict__ Wk, const float* __restrict__ bk,
            const float* __restrict__ Wv, ushort* __restrict__ wp)
{
    __shared__ float sw[48*129];                   // 24768 B
    const int lane = threadIdx.x;
    const int bx   = blockIdx.x;
    const int h    = bx / 40;
    const int r40  = bx % 40;
    const int tile = r40 >> 2;
    const int ks   = r40 & 3;
    const int c    = lane & 15;
    const int quad = lane >> 4;
    const int f0   = ks*32 + quad*8;

    float val[8];
    #pragma unroll
    for (int j = 0; j < 8; ++j) val[j] = 0.f;

    if (tile < 8) {                                // A-frag: M[16t+c][32ks+quad*8+j]
        const float* wq = Wq + (size_t)h*FF*FF;
        const float* wk = Wk + (size_t)h*FF*FF;
        float* wqs = sw;                           // 16 x 129
        float* wks = sw + 16*129;                  // 32 x 129
        for (int i = lane; i < 16*128; i += 64)
            wqs[(i>>7)*129 + (i&127)] = wq[(size_t)(tile*16 + (i>>7))*FF + (i&127)];
        for (int i = lane; i < 32*128; i += 64)
            wks[(i>>7)*129 + (i&127)] = wk[(size_t)(ks*32 + (i>>7))*FF + (i&127)];
        __syncthreads();
        for (int e = 0; e < FF; ++e) {
            float qv = wqs[c*129 + e];
            #pragma unroll
            for (int j = 0; j < 8; ++j)
                val[j] += wks[(quad*8 + j)*129 + e] * qv;
        }
    } else if (tile == 8) {                        // col0 = u = Wq bk, col1 = v = Wk bq
        const float* wq = Wq + (size_t)h*FF*FF;
        const float* wk = Wk + (size_t)h*FF*FF;
        float pu[8], pv[8];
        #pragma unroll
        for (int j = 0; j < 8; ++j) { pu[j] = 0.f; pv[j] = 0.f; }
        for (int ee = 0; ee < 8; ++ee) {           // lane c handles e in [8c, 8c+8)
            int e = c*8 + ee;
            float bkk = bk[h*FF + e], bqq = bq[h*FF + e];
            #pragma unroll
            for (int j = 0; j < 8; ++j) {
                pu[j] += wq[(size_t)(f0+j)*FF + e] * bkk;
                pv[j] += wk[(size_t)(f0+j)*FF + e] * bqq;
            }
        }
        #pragma unroll
        for (int m = 1; m < 16; m <<= 1) {         // reduce over c (quad preserved)
            #pragma unroll
            for (int j = 0; j < 8; ++j) {
                pu[j] += __shfl_xor(pu[j], m);
                pv[j] += __shfl_xor(pv[j], m);
            }
        }
        if (c == 0) {
            #pragma unroll
            for (int j = 0; j < 8; ++j) val[j] = pu[j];
        } else if (c == 1) {
            #pragma unroll
            for (int j = 0; j < 8; ++j) val[j] = pv[j];
        }
        if (ks == 0) {                             // c = bq.bk, wave-parallel
            float s = bq[h*FF + lane*2]*bk[h*FF + lane*2]
                    + bq[h*FF + lane*2 + 1]*bk[h*FF + lane*2 + 1];
            #pragma unroll
            for (int m = 1; m < 64; m <<= 1) s += __shfl_xor(s, m);
            if (lane == 0) ((float*)(wp + 327680))[h] = s;
        }
    } else {                                       // Wv B-frag
        const float* wv = Wv + (size_t)h*FF*DVn;
        #pragma unroll
        for (int j = 0; j < 8; ++j) val[j] = wv[(size_t)(f0+j)*DVn + c];
    }

    ushort hi[8], lo[8];
    #pragma unroll
    for (int j = 0; j < 8; ++j) {
        ushort hb = bf_hi(val[j]);
        hi[j] = hb;
        lo[j] = bf_hi(val[j] - bf_f(hb));
    }
    size_t base = (size_t)h*40960 + (size_t)tile*4096 + ks*1024 + lane*8;
    *(ushort4*)(wp + base)       = make_ushort4(hi[0],hi[1],hi[2],hi[3]);
    *(ushort4*)(wp + base + 4)   = make_ushort4(hi[4],hi[5],hi[6],hi[7]);
    *(ushort4*)(wp + base + 512) = make_ushort4(lo[0],lo[1],lo[2],lo[3]);
    *(ushort4*)(wp + base + 516) = make_ushort4(lo[4],lo[5],lo[6],lo[7]);
}

// ---------------- fused attention ----------------
// v4: S = x.(M.x^T). G = M.x^T keeps m on lanes producer AND consumer -> NO lane
//     transpose: G C-frag -> B-frag via contiguous b64 LDS writes (16/thread vs 64
//     scalar), and each wave reads only its own col-panel (8 b128 vs 32).
//     Wave w: G f-rows [32w,32w+32) (M tiles 2w,2w+1, A-frags); S col-tile w.
//     Trunc-based hi/lo splits (compensated); tu read as float4.
// LDS (ushorts; 53248 B -> 3 blocks/CU):
//   xl panels [mt4][ks4] @0 (persist, stride 528)
//   x-hi staging @8448 (dead after reg preload) == G-hi panels @8448 (GB0)
//   G-lo @16896 (GDEL=8448); satt bf16 [64][88] @8448 (overlay G-hi)
//   vf @25344 (2 ks panels x 512); tu[64],tv[64] fp32 @float 13184/13248
#define PX    528
#define XL0   0
#define XH0   8448
#define GB0   8448
#define GDEL  8448
#define SATT0 8448
#define SATTP 88
#define VF0   25344
#define TU0   13184
#define TV0   13248
#define LDS_FLOATS 13312

__global__ __launch_bounds__(256, 3)
void attn_fused(const float* __restrict__ hid, const ushort* __restrict__ wp,
                const float* __restrict__ ccp, const float* __restrict__ bv,
                float* __restrict__ out)
{
    __shared__ __align__(16) float lds[LDS_FLOATS];
    ushort* us = (ushort*)lds;
    float*  tu = lds + TU0;
    float*  tv = lds + TV0;

    const int t    = threadIdx.x;
    const int b    = blockIdx.x;
    const int lane = t & 63;
    const int w    = t >> 6;
    const int c16  = lane & 15;
    const int quad = lane >> 4;

    // ---- stage x -> bf16 hi/lo A-frag panels, ONCE per b (trunc split: hi err
    //      compensated by lo; rows >= 50 garbage, masked later) ----
    {
        const float4* src = (const float4*)(hid + (size_t)b * (LL*FF));
        for (int i = t; i < 1600; i += 256) {
            float4 v = src[i];
            int l = i >> 5, f0 = (i & 31) * 4;
            int slot = ((l>>4)*4 + (f0>>5))*PX + ((l&15) + 16*((f0&31)>>3))*8 + (f0&7);
            ushort4 hv, lv;
            uint ux;
            ux = __float_as_uint(v.x); hv.x = (ushort)(ux>>16);
            lv.x = (ushort)(__float_as_uint(v.x - __uint_as_float(ux & 0xFFFF0000u))>>16);
            ux = __float_as_uint(v.y); hv.y = (ushort)(ux>>16);
            lv.y = (ushort)(__float_as_uint(v.y - __uint_as_float(ux & 0xFFFF0000u))>>16);
            ux = __float_as_uint(v.z); hv.z = (ushort)(ux>>16);
            lv.z = (ushort)(__float_as_uint(v.z - __uint_as_float(ux & 0xFFFF0000u))>>16);
            ux = __float_as_uint(v.w); hv.w = (ushort)(ux>>16);
            lv.w = (ushort)(__float_as_uint(v.w - __uint_as_float(ux & 0xFFFF0000u))>>16);
            *(ushort4*)(us + XH0 + slot) = hv;
            *(ushort4*)(us + XL0 + slot) = lv;
        }
    }
    __syncthreads();

    // ---- preload ALL 16 x-hi frags into registers (staging region becomes G) ----
    bf16x8 xh[16];
    #pragma unroll
    for (int i = 0; i < 16; ++i)
        xh[i] = *(const bf16x8*)(us + XH0 + i*PX + lane*8);
    __syncthreads();

    #pragma unroll 1
    for (int h = 0; h < HH; ++h) {
        // ---- G = M.x^T (bf16x3), U/V = x.[u|v], x.Wv. Wave w: M f-tiles {2w,2w+1} ----
        f32x4 aG[2][4], aU, aV;
        #pragma unroll
        for (int i = 0; i < 2; ++i)
            #pragma unroll
            for (int m = 0; m < 4; ++m) aG[i][m] = (f32x4){0.f,0.f,0.f,0.f};
        aU = (f32x4){0.f,0.f,0.f,0.f};
        aV = (f32x4){0.f,0.f,0.f,0.f};

        const ushort* wb = wp + (size_t)h*40960 + lane*8;
        #define WFRG(tt,kk,pp) (*(const bf16x8*)(wb + (size_t)(tt)*4096 + (kk)*1024 + (pp)*512))

        #pragma unroll
        for (int ks = 0; ks < 4; ++ks) {
            bf16x8 m0h = WFRG(2*w,   ks, 0), m0l = WFRG(2*w,   ks, 1);
            bf16x8 m1h = WFRG(2*w+1, ks, 0), m1l = WFRG(2*w+1, ks, 1);
            bf16x8 uvh = WFRG(8, ks, 0);
            bf16x8 vvh = WFRG(9, ks, 0);
            #pragma unroll
            for (int mt = 0; mt < 4; ++mt) {
                bf16x8 bh = xh[mt*4 + ks];                       // x as B (m on lanes)
                bf16x8 bl = *(const bf16x8*)(us + XL0 + (mt*4 + ks)*PX + lane*8);
                aG[0][mt] = __builtin_amdgcn_mfma_f32_16x16x32_bf16(m0h, bh, aG[0][mt], 0,0,0);
                aG[0][mt] = __builtin_amdgcn_mfma_f32_16x16x32_bf16(m0l, bh, aG[0][mt], 0,0,0);
                aG[0][mt] = __builtin_amdgcn_mfma_f32_16x16x32_bf16(m0h, bl, aG[0][mt], 0,0,0);
                aG[1][mt] = __builtin_amdgcn_mfma_f32_16x16x32_bf16(m1h, bh, aG[1][mt], 0,0,0);
                aG[1][mt] = __builtin_amdgcn_mfma_f32_16x16x32_bf16(m1l, bh, aG[1][mt], 0,0,0);
                aG[1][mt] = __builtin_amdgcn_mfma_f32_16x16x32_bf16(m1h, bl, aG[1][mt], 0,0,0);
                if (mt == w) {                                    // x as A (l on lanes)
                    aU = __builtin_amdgcn_mfma_f32_16x16x32_bf16(bh, uvh, aU, 0,0,0);
                    aV = __builtin_amdgcn_mfma_f32_16x16x32_bf16(bh, vvh, aV, 0,0,0);
                    aV = __builtin_amdgcn_mfma_f32_16x16x32_bf16(bl, vvh, aV, 0,0,0);
                }
            }
        }

        // ---- epilogue: G C-frag -> B-frag panels via CONTIGUOUS b64 writes ----
        // value (f = 16*(2w+i) + quad*4 + r, m = 16mt + c16) -> panel (mt*4 + w),
        // group = c16 + 16*(2i + (quad>>1)), j = (quad&1)*4 + r  (r contiguous!)
        {
            #pragma unroll
            for (int i = 0; i < 2; ++i) {
                #pragma unroll
                for (int mt = 0; mt < 4; ++mt) {
                    uint u0 = __float_as_uint(aG[i][mt][0]);
                    uint u1 = __float_as_uint(aG[i][mt][1]);
                    uint u2 = __float_as_uint(aG[i][mt][2]);
                    uint u3 = __float_as_uint(aG[i][mt][3]);
                    uint hw0 = (u0>>16) | (u1 & 0xFFFF0000u);
                    uint hw1 = (u2>>16) | (u3 & 0xFFFF0000u);
                    float l0 = aG[i][mt][0] - __uint_as_float(u0 & 0xFFFF0000u);
                    float l1 = aG[i][mt][1] - __uint_as_float(u1 & 0xFFFF0000u);
                    float l2 = aG[i][mt][2] - __uint_as_float(u2 & 0xFFFF0000u);
                    float l3 = aG[i][mt][3] - __uint_as_float(u3 & 0xFFFF0000u);
                    uint lw0 = (__float_as_uint(l0)>>16) | (__float_as_uint(l1) & 0xFFFF0000u);
                    uint lw1 = (__float_as_uint(l2)>>16) | (__float_as_uint(l3) & 0xFFFF0000u);
                    ushort* dst = us + GB0 + (mt*4 + w)*PX
                                  + (c16 + 16*(2*i + (quad>>1)))*8 + (quad&1)*4;
                    *(uint2*)dst          = make_uint2(hw0, hw1);
                    *(uint2*)(dst + GDEL) = make_uint2(lw0, lw1);
                }
            }
            if (c16 < 2) {
                float* dst = (c16 == 0) ? tu : tv;
                #pragma unroll
                for (int r = 0; r < 4; ++r) dst[w*16 + quad*4 + r] = aU[r];
            }
            float bvv = bv[h*DVn + c16];
            int ksp = w >> 1;
            #pragma unroll
            for (int r = 0; r < 4; ++r) {
                int m  = w*16 + quad*4 + r;
                int mm = (w&1)*16 + quad*4 + r;
                int Lp = c16 + 16*(mm >> 3);
                us[VF0 + ksp*512 + Lp*8 + (mm & 7)] = (m < LL) ? bf_hi(aV[r] + bvv) : (ushort)0;
            }
        }
        __syncthreads();                            // B0: G/tu/tv/vf visible

        // ---- S = x.G (bf16x3). Wave w reads ONLY its own col-panels (w*4 + ks) ----
        f32x4 sc[4];
        #pragma unroll
        for (int m = 0; m < 4; ++m) sc[m] = (f32x4){0.f,0.f,0.f,0.f};

        #pragma unroll
        for (int ks = 0; ks < 4; ++ks) {
            const ushort* gb = us + GB0 + (w*4 + ks)*PX + lane*8;
            bf16x8 gh = *(const bf16x8*)gb;
            bf16x8 gl = *(const bf16x8*)(gb + GDEL);
            #pragma unroll
            for (int mt = 0; mt < 4; ++mt) {
                bf16x8 ah = xh[mt*4 + ks];
                bf16x8 al = *(const bf16x8*)(us + XL0 + (mt*4 + ks)*PX + lane*8);
                sc[mt] = __builtin_amdgcn_mfma_f32_16x16x32_bf16(ah, gh, sc[mt], 0,0,0);
                sc[mt] = __builtin_amdgcn_mfma_f32_16x16x32_bf16(al, gh, sc[mt], 0,0,0);
                sc[mt] = __builtin_amdgcn_mfma_f32_16x16x32_bf16(ah, gl, sc[mt], 0,0,0);
            }
        }

        // ---- rank-1/const terms, leaky, column softmax (tu via float4) ----
        const float cc  = ccp[h];
        const int mcol  = w*16 + c16;
        const float tvv = tv[mcol] + cc;
        float mx = -INFINITY;
        #pragma unroll
        for (int mt = 0; mt < 4; ++mt) {
            const float4 tq = *(const float4*)(tu + mt*16 + quad*4);
            float tqa[4] = {tq.x, tq.y, tq.z, tq.w};
            #pragma unroll
            for (int r = 0; r < 4; ++r) {
                int l = mt*16 + quad*4 + r;
                float s = sc[mt][r] + tqa[r] + tvv;
                s = (s > 0.f) ? s : 0.1f*s;
                sc[mt][r] = s;
                if (l < LL) mx = fmaxf(mx, s);
            }
        }
        mx = fmaxf(mx, __shfl_xor(mx, 16));
        mx = fmaxf(mx, __shfl_xor(mx, 32));
        float sum = 0.f;
        #pragma unroll
        for (int mt = 0; mt < 4; ++mt)
            #pragma unroll
            for (int r = 0; r < 4; ++r) {
                int l = mt*16 + quad*4 + r;
                float p = (l < LL) ? __expf(sc[mt][r] - mx) : 0.f;
                sc[mt][r] = p;
                sum += p;
            }
        sum += __shfl_xor(sum, 16);
        sum += __shfl_xor(sum, 32);
        float inv = 1.0f / sum;

        __syncthreads();                            // B1: all G reads done (satt overlays G-hi)

        // satt bf16 [64][88] overlaid on G-hi; cols >=50 zeroed
        #pragma unroll
        for (int mt = 0; mt < 4; ++mt)
            #pragma unroll
            for (int r = 0; r < 4; ++r) {
                int l = mt*16 + quad*4 + r;
                us[SATT0 + l*SATTP + mcol] = (mcol < LL) ? bf_hi(sc[mt][r] * inv) : (ushort)0;
            }
        __syncthreads();                            // B2: satt visible

        // ---- out = relu(att.V) via MFMA; wave w owns l-tile w ----
        f32x4 ao = (f32x4){0.f,0.f,0.f,0.f};
        #pragma unroll
        for (int ksp = 0; ksp < 2; ++ksp) {
            bf16x8 af = *(const bf16x8*)(us + SATT0 + (w*16 + c16)*SATTP + ksp*32 + quad*8);
            bf16x8 bf = *(const bf16x8*)(us + VF0 + ksp*512 + lane*8);
            ao = __builtin_amdgcn_mfma_f32_16x16x32_bf16(af, bf, ao, 0,0,0);
        }
        #pragma unroll
        for (int r = 0; r < 4; ++r) {
            int l = w*16 + quad*4 + r;
            if (l < LL)
                out[(size_t)b*(LL*FF) + l*FF + h*DVn + c16] = fmaxf(ao[r], 0.f);
        }
        __syncthreads();                            // B3: protect satt/vf/tu/tv/G for next h
    }
}

extern "C" void kernel_launch(void* const* d_in, const int* in_sizes, int n_in,
                              void* d_out, int out_size, void* d_ws, size_t ws_size,
                              hipStream_t stream)
{
    const float* hid = (const float*)d_in[0];
    const float* Wq  = (const float*)d_in[1];
    const float* bq  = (const float*)d_in[2];
    const float* Wk  = (const float*)d_in[3];
    const float* bk  = (const float*)d_in[4];
    const float* Wv  = (const float*)d_in[5];
    const float* bv  = (const float*)d_in[6];
    float* o    = (float*)d_out;
    ushort* wp  = (ushort*)d_ws;                       // 655392 B used
    const float* ccp = (const float*)(wp + 327680);

    pack_w<<<dim3(320), dim3(64), 0, stream>>>(Wq, bq, Wk, bk, Wv, wp);
    attn_fused<<<dim3(NB), dim3(256), 0, stream>>>(hid, wp, ccp, bv, o);
}